// Round 9
// baseline (151.869 us; speedup 1.0000x reference)
//
#include <hip/hip_runtime.h>
#include <hip/hip_fp16.h>
#include <math.h>

// DigitCaps dynamic routing, MI355X (gfx950). Round 9.
// B=256, I=1152 (dim 8), O=10 (dim 16), 3 routing iters.
//
// R8 post-mortem: k_uhat write-drain-bound at 2.1 TB/s, 21% occupancy
// (LDS 48 KB = 3 blocks/CU); k_route ~48 us/pass streaming 47 MB via 45
// stride-4KB dword loads/thread (256 B per wave-load, no prefetch).
//
// This round:
//  - k_uhat: bb loop split into 2 halves of 8 with partial-flush between
//    -> pacc 40->20 KB, LDS 28 KB -> 5 blocks/CU. launch_bounds STAYS (256,4)
//    (R6/R7: min-waves>=5 shrinks the per-wave VGPR budget -> scratch spills).
//  - ws layout: o=0..7 packed as uint4 (4x half2), o=8..9 as dword, both
//    thread-major -> k_uhat 2 stores/bb (was 5), k_route 2 loads/ch (was 5,
//    now 1KB/wave dwordx4) + explicit next-chunk double-buffer prefetch.
//  - b_ij identity: logits at iter k = u.(v0+..+v_{k-1}) = u.vsum.
//
// Pipeline: k_uhat -> k_route<1> (inline vsum0) -> k_route<2> -> k_final.

constexpr int Bc  = 256;
constexpr int Ic  = 1152;
constexpr int Oc  = 10;
constexpr int DOc = 16;
constexpr int ODc = 160;
constexpr int ITILES = 72;

// Sum over the aligned 16-lane group, result in all 16 lanes. Pure VALU (DPP).
__device__ __forceinline__ float dpp16_sum(float v) {
    int s;
    s = __builtin_amdgcn_update_dpp(0, __float_as_int(v), 0xB1, 0xF, 0xF, true);
    v += __int_as_float(s);
    s = __builtin_amdgcn_update_dpp(0, __float_as_int(v), 0x4E, 0xF, 0xF, true);
    v += __int_as_float(s);
    s = __builtin_amdgcn_update_dpp(0, __float_as_int(v), 0x124, 0xF, 0xF, true);
    v += __int_as_float(s);
    s = __builtin_amdgcn_update_dpp(0, __float_as_int(v), 0x128, 0xF, 0xF, true);
    v += __int_as_float(s);
    return v;
}

__device__ __forceinline__ unsigned int pack_h2(float a, float b) {
    __half2 h = __floats2half2_rn(a, b);
    unsigned int u;
    __builtin_memcpy(&u, &h, 4);
    return u;
}

__device__ __forceinline__ float2 unpack_h2(unsigned int u) {
    __half2 h;
    __builtin_memcpy(&h, &u, 4);
    return __half22float2(h);
}

// ---------------------------------------------------------------- K1
// grid 72 itiles x 16 btiles, 256 threads. Thread (il=t>>4, d=t&15) covers
// capsule i = itile*16+il, out-dim d over 16 b. bb loop split in halves so
// pacc is 20 KB -> LDS 28 KB -> 5 blocks/CU.
__global__ __launch_bounds__(256, 4) void k_uhat(const float* __restrict__ x,
                                                 const float* __restrict__ W,
                                                 uint4* __restrict__ ws4,
                                                 unsigned int* __restrict__ ws1,
                                                 float* __restrict__ partial) {
    const int bx    = blockIdx.x;
    const int itile = bx % ITILES;
    const int btile = bx / ITILES;
    const int t     = threadIdx.x;
    const int d     = t & 15;
    const int il    = t >> 4;
    const int w     = t >> 6;
    const int i     = itile * 16 + il;
    const int b0    = btile * 16;

    __shared__ __align__(16) float xs[16 * 128];       //  8 KB [bb][il*8+k]
    __shared__ __align__(16) float pacc[4 * 8 * ODc];  // 20 KB [w][bb8][od]

    // stage x[b0:b0+16][itile*16:+16][8]
#pragma unroll
    for (int j = 0; j < 2; ++j) {
        int e  = t + j * 256;
        int bb = e >> 5;
        int r  = e & 31;
        ((float4*)xs)[e] =
            ((const float4*)(x + (size_t)(b0 + bb) * (Ic * 8) + itile * 128))[r];
    }

    // W fragment for (i, d): 10 o x 8 k = 80 floats (L1/L2-resident reuse)
    float4 wr[20];
    {
        const float4* wp = (const float4*)(W + (((size_t)i * Oc) * DOc + d) * 8);
#pragma unroll
        for (int o = 0; o < Oc; ++o) {
            wr[2 * o]     = wp[o * 32];
            wr[2 * o + 1] = wp[o * 32 + 1];
        }
    }
    __syncthreads();

    const int chg   = i >> 6;                 // global chunk 0..17
    const int t_pos = (i & 63) * 16 + d;      // 0..1023, consecutive over t

#pragma unroll 1
    for (int half = 0; half < 2; ++half) {
#pragma unroll 1
        for (int bb8 = 0; bb8 < 8; ++bb8) {
            const int bb = half * 8 + bb8;
            const int b  = b0 + bb;
            const float4 xa = *((const float4*)(xs + bb * 128 + il * 8));
            const float4 xb = *((const float4*)(xs + bb * 128 + il * 8 + 4));
            float u[Oc];
#pragma unroll
            for (int o = 0; o < Oc; ++o) {
                float4 w0 = wr[2 * o], w1 = wr[2 * o + 1];
                u[o] = w0.x * xa.x + w0.y * xa.y + w0.z * xa.z + w0.w * xa.w +
                       w1.x * xb.x + w1.y * xb.y + w1.z * xb.z + w1.w * xb.w;
            }
            // packed ws write: one dwordx4 (o=0..7) + one dword (o=8,9)
            const size_t idx = ((size_t)b * 18 + chg) * 1024 + t_pos;
            ws4[idx] = make_uint4(pack_h2(u[0], u[1]), pack_h2(u[2], u[3]),
                                  pack_h2(u[4], u[5]), pack_h2(u[6], u[7]));
            ws1[idx] = pack_h2(u[8], u[9]);
            // reduce over the wave's 4 il values; lane<16 holds (o,d) sums
#pragma unroll
            for (int o = 0; o < Oc; ++o) {
                float a = u[o];
                a += __shfl_xor(a, 16);
                a += __shfl_xor(a, 32);
                if ((t & 63) < 16) pacc[(w * 8 + bb8) * ODc + o * 16 + d] = a;
            }
        }
        __syncthreads();
        // flush this half: 8 bb x 160 od = 1280 floats, 5 per thread
#pragma unroll
        for (int j = 0; j < 5; ++j) {
            int e = t + j * 256;              // bb8*160 + od
            float s = pacc[e] + pacc[1280 + e] + pacc[2560 + e] + pacc[3840 + e];
            partial[(size_t)itile * (Bc * ODc) + (b0 + half * 8) * ODc + e] = s;
        }
        __syncthreads();
    }
}

// ---------------------------------------------------------------- K2/K3
// grid 512 = b x i-half, 1024 threads, 2 blocks/CU (32 waves).
// PASS 1: vsum = squash(0.1 * sum_{p<72} partial[p]); also written to vsumg.
// PASS 2: vsum = vsumg + squash(spart1[0]+spart1[1]).
template <int PASS>
__global__ __launch_bounds__(1024, 8) void k_route(const uint4* __restrict__ ws4,
                                                   const unsigned int* __restrict__ ws1,
                                                   const float* __restrict__ partial,
                                                   const float* __restrict__ sprev,
                                                   float* __restrict__ vsumg,
                                                   float* __restrict__ spart) {
    const int bx  = blockIdx.x;
    const int b   = bx >> 1;
    const int h   = bx & 1;
    const int t   = threadIdx.x;
    const int d   = t & 15;
    const int wid = t >> 6;

    __shared__ float vs_s[ODc];
    __shared__ float red4[4 * ODc];
    __shared__ float red[16 * ODc];     // 10 KB

    // ---- inline vsum computation ----
    if (PASS == 1) {
        const int team = t >> 8;        // 0..3, each reduces 18 of 72 partials
        const int tt   = t & 255;
        if (tt < ODc) {
            float s = 0.f;
            const float* pb = partial + (size_t)team * 18 * (Bc * ODc) + b * ODc + tt;
#pragma unroll 6
            for (int p = 0; p < 18; ++p) s += pb[(size_t)p * (Bc * ODc)];
            red4[team * ODc + tt] = s;
        }
        __syncthreads();
        if (t < ODc) {
            float s = (red4[t] + red4[ODc + t] + red4[2 * ODc + t] +
                       red4[3 * ODc + t]) * 0.1f;
            float sq = dpp16_sum(s * s);
            float v = s * (sq / ((1.f + sq) * sqrtf(sq)));
            vs_s[t] = v;
            vsumg[b * ODc + t] = v;     // both h-blocks write same value
        }
    } else {
        if (t < ODc) {
            float s = sprev[b * ODc + t] + sprev[(size_t)(Bc * ODc) + b * ODc + t];
            float sq = dpp16_sum(s * s);
            float v = s * (sq / ((1.f + sq) * sqrtf(sq)));
            vs_s[t] = vsumg[b * ODc + t] + v;
        }
    }
    __syncthreads();

    float vsr[Oc];
#pragma unroll
    for (int o = 0; o < Oc; ++o) vsr[o] = vs_s[o * 16 + d];
    float acc[Oc];
#pragma unroll
    for (int o = 0; o < Oc; ++o) acc[o] = 0.f;

    const uint4* wb4        = ws4 + ((size_t)b * 18 + h * 9) * 1024 + t;
    const unsigned int* wb1 = ws1 + ((size_t)b * 18 + h * 9) * 1024 + t;

    // double-buffered chunk loads: 1 dwordx4 + 1 dword per chunk
    uint4 curA        = wb4[0];
    unsigned int curB = wb1[0];
#pragma unroll 1
    for (int ch = 0; ch < 9; ++ch) {
        uint4 nxtA;
        unsigned int nxtB;
        if (ch < 8) {
            nxtA = wb4[(ch + 1) * 1024];
            nxtB = wb1[(ch + 1) * 1024];
        }
        float uo[Oc];
        {
            float2 f;
            f = unpack_h2(curA.x); uo[0] = f.x; uo[1] = f.y;
            f = unpack_h2(curA.y); uo[2] = f.x; uo[3] = f.y;
            f = unpack_h2(curA.z); uo[4] = f.x; uo[5] = f.y;
            f = unpack_h2(curA.w); uo[6] = f.x; uo[7] = f.y;
            f = unpack_h2(curB);   uo[8] = f.x; uo[9] = f.y;
        }
        // logits via DPP 16-lane reduce (VALU, no DS traffic)
        float c[Oc];
#pragma unroll
        for (int o = 0; o < Oc; ++o) c[o] = dpp16_sum(uo[o] * vsr[o]);
        float m = c[0];
#pragma unroll
        for (int o = 1; o < Oc; ++o) m = fmaxf(m, c[o]);
        float se = 0.f;
#pragma unroll
        for (int o = 0; o < Oc; ++o) {
            c[o] = __expf(c[o] - m);
            se += c[o];
        }
        const float inv = 1.f / se;
#pragma unroll
        for (int o = 0; o < Oc; ++o) acc[o] += (c[o] * inv) * uo[o];
        curA = nxtA;
        curB = nxtB;
    }
    // block reduce over iblk
#pragma unroll
    for (int o = 0; o < Oc; ++o) {
        float a = acc[o];
        a += __shfl_xor(a, 16);
        a += __shfl_xor(a, 32);
        if ((t & 63) < 16) red[wid * ODc + o * 16 + d] = a;
    }
    __syncthreads();
    if (t < ODc) {
        float s = 0.f;
#pragma unroll
        for (int w = 0; w < 16; ++w) s += red[w * ODc + t];
        spart[(size_t)h * (Bc * ODc) + b * ODc + t] = s;
    }
}

// ---------------------------------------------------------------- K4
__global__ __launch_bounds__(192) void k_final(const float* __restrict__ spart,
                                               float* __restrict__ out) {
    const int b = blockIdx.x;
    const int t = threadIdx.x;
    if (t >= ODc) return;
    float s = spart[b * ODc + t] + spart[(size_t)(Bc * ODc) + b * ODc + t];
    float sq = dpp16_sum(s * s);
    float v = s * (sq / ((1.f + sq) * sqrtf(sq)));
    out[(size_t)b * ODc + t] = v;
}

// ---------------------------------------------------------------- fallback
__global__ void __launch_bounds__(1024, 4)
digitcaps_fallback(const float* __restrict__ x, const float* __restrict__ W,
                   float* __restrict__ out) {
    const int b = blockIdx.x, t = threadIdx.x;
    const int lane = t & 63, wid = t >> 6, d = t & 15, iblk = t >> 4;
    __shared__ __align__(16) float xs[Ic * 8];
    __shared__ __align__(16) float red[16 * ODc];
    __shared__ __align__(16) float svec[ODc], vcur[ODc], vsum[ODc];
    {
        const float4* xg = (const float4*)(x + (size_t)b * (Ic * 8));
        float4* xl = (float4*)xs;
        for (int j = t; j < Ic * 2; j += 1024) xl[j] = xg[j];
    }
    if (t < ODc) vsum[t] = 0.f;
    __syncthreads();
    float acc[Oc], vsr[Oc];
    for (int it = 0; it < 3; ++it) {
#pragma unroll
        for (int o = 0; o < Oc; ++o) { acc[o] = 0.f; vsr[o] = vsum[o * 16 + d]; }
#pragma unroll 1
        for (int chk = 0; chk < 18; ++chk) {
            const int i = chk * 64 + iblk;
            const float4 xa = ((const float4*)(xs + i * 8))[0];
            const float4 xb = ((const float4*)(xs + i * 8))[1];
            const float* wb = W + (((size_t)i * Oc) * DOc + d) * 8;
            float uo[Oc];
#pragma unroll
            for (int o = 0; o < Oc; ++o) {
                const float4* wp = (const float4*)(wb + o * 128);
                float4 w0 = wp[0], w1 = wp[1];
                uo[o] = w0.x * xa.x + w0.y * xa.y + w0.z * xa.z + w0.w * xa.w +
                        w1.x * xb.x + w1.y * xb.y + w1.z * xb.z + w1.w * xb.w;
            }
            float cc[Oc];
            if (it > 0) {
#pragma unroll
                for (int o = 0; o < Oc; ++o) cc[o] = dpp16_sum(uo[o] * vsr[o]);
                float m = cc[0];
#pragma unroll
                for (int o = 1; o < Oc; ++o) m = fmaxf(m, cc[o]);
                float se = 0.f;
#pragma unroll
                for (int o = 0; o < Oc; ++o) { cc[o] = __expf(cc[o] - m); se += cc[o]; }
                float inv = 1.f / se;
#pragma unroll
                for (int o = 0; o < Oc; ++o) acc[o] += cc[o] * inv * uo[o];
            } else {
#pragma unroll
                for (int o = 0; o < Oc; ++o) acc[o] += 0.1f * uo[o];
            }
        }
#pragma unroll
        for (int o = 0; o < Oc; ++o) {
            float a = acc[o];
            a += __shfl_xor(a, 16);
            a += __shfl_xor(a, 32);
            if (lane < 16) red[wid * ODc + o * 16 + lane] = a;
        }
        __syncthreads();
        if (t < ODc) {
            float s = 0.f;
#pragma unroll
            for (int w = 0; w < 16; ++w) s += red[w * ODc + t];
            svec[t] = s;
        }
        __syncthreads();
        if (t < Oc) {
            float sq = 0.f;
#pragma unroll
            for (int dd = 0; dd < DOc; ++dd) sq += svec[t * 16 + dd] * svec[t * 16 + dd];
            float sc = sq / ((1.f + sq) * sqrtf(sq));
#pragma unroll
            for (int dd = 0; dd < DOc; ++dd) {
                float v = svec[t * 16 + dd] * sc;
                vcur[t * 16 + dd] = v;
                vsum[t * 16 + dd] += v;
            }
        }
        __syncthreads();
    }
    if (t < ODc) out[(size_t)b * ODc + t] = vcur[t];
}

// ---------------------------------------------------------------- launcher
extern "C" void kernel_launch(void* const* d_in, const int* in_sizes, int n_in,
                              void* d_out, int out_size, void* d_ws, size_t ws_size,
                              hipStream_t stream) {
    (void)in_sizes; (void)n_in; (void)out_size;
    const float* x = (const float*)d_in[0];   // [256,1152,8]
    const float* W = (const float*)d_in[1];   // [1152,10,16,8]
    float* out     = (float*)d_out;           // [256,10,16]

    const size_t WS4_B  = (size_t)Bc * 18 * 1024 * 16;                // 75.50 MB
    const size_t WS1_B  = (size_t)Bc * 18 * 1024 * 4;                 // 18.87 MB
    const size_t PART_B = (size_t)ITILES * Bc * ODc * sizeof(float);  // 11.80 MB
    const size_t SP1_B  = (size_t)2 * Bc * ODc * sizeof(float);       //  0.33 MB
    const size_t SP2_B  = (size_t)2 * Bc * ODc * sizeof(float);       //  0.33 MB
    const size_t VSUM_B = (size_t)Bc * ODc * sizeof(float);           //  0.16 MB

    char* p = (char*)d_ws;
    uint4* ws4        = (uint4*)p;                 p += WS4_B;
    unsigned int* ws1 = (unsigned int*)p;          p += WS1_B;
    float* partial    = (float*)p;                 p += PART_B;
    float* spart1     = (float*)p;                 p += SP1_B;
    float* spart2     = (float*)p;                 p += SP2_B;
    float* vsumg      = (float*)p;

    if (ws_size >= WS4_B + WS1_B + PART_B + SP1_B + SP2_B + VSUM_B) {
        hipLaunchKernelGGL(k_uhat, dim3(ITILES * 16), dim3(256), 0, stream,
                           x, W, ws4, ws1, partial);
        hipLaunchKernelGGL((k_route<1>), dim3(512), dim3(1024), 0, stream,
                           ws4, ws1, partial, nullptr, vsumg, spart1);
        hipLaunchKernelGGL((k_route<2>), dim3(512), dim3(1024), 0, stream,
                           ws4, ws1, nullptr, spart1, vsumg, spart2);
        hipLaunchKernelGGL(k_final, dim3(Bc), dim3(192), 0, stream,
                           spart2, out);
    } else {
        hipLaunchKernelGGL(digitcaps_fallback, dim3(Bc), dim3(1024), 0, stream,
                           x, W, out);
    }
}